// Round 15
// baseline (223.562 us; speedup 1.0000x reference)
//
#include <hip/hip_runtime.h>
#include <cstdint>
#include <cstddef>

// ---------------------------------------------------------------------------
// ChatGPTAttention: x[2,2048,1024] -> QKV proj -> causal MHA (16 heads, dk=64)
//                   -> O proj. bf16 MFMA pipeline, fp32 accumulate.
// Q pre-scaled by 1/8 in QKV-GEMM epilogue; V written transposed by the same
// epilogue (transpose_v eliminated, R14: 204.6 -> 190.8us).
// LESSONS: (R5) LDS row stride multiple of 8 ushorts. (R6/R8) XOR swizzle for
// DMA-staged LDS. (R8/R9) dbuf DMA needs occupancy (BK=32). (R11/R12) direct
// global frags OK at 1x redundancy only. (R12/R13) 1-wave attn = one latency
// chain, too little overlap. (R7-R14) 4-wave shared-tile attn = barrier-locked
// + 4x redundant frag reads -> 46us floor.
// R15 v11: SPLIT-K attn — 4 waves, same 32-q tile, DISJOINT kv tiles
// (wave w: t = w, w+4, ...). No-max softmax => partials just add; single
// end-of-kernel LDS reduction. Zero main-loop barriers; K+V direct global 1x.
// ---------------------------------------------------------------------------

typedef __attribute__((ext_vector_type(8))) short bf16x8;   // MFMA A/B frag
typedef __attribute__((ext_vector_type(4))) float f32x4;    // MFMA C/D frag
typedef __attribute__((ext_vector_type(4))) unsigned int u32x4;   // 16B copy
typedef __attribute__((ext_vector_type(4))) unsigned short u16x4; // 8B store
typedef __attribute__((ext_vector_type(8))) unsigned short u16x8; // 16B store

__device__ __forceinline__ unsigned short f2b(float f) {  // RNE f32->bf16
  unsigned int u = __float_as_uint(f);
  u = u + 0x7FFFu + ((u >> 16) & 1u);
  return (unsigned short)(u >> 16);
}
__device__ __forceinline__ unsigned short f2b_trunc(float f) {  // truncate
  return (unsigned short)(__float_as_uint(f) >> 16);
}

// async global->LDS DMA, 16B per lane; LDS dest = wave base + lane*16
__device__ __forceinline__ void gl_lds16(const unsigned short* g, unsigned short* s) {
  __builtin_amdgcn_global_load_lds((const __attribute__((address_space(1))) void*)g,
                                   (__attribute__((address_space(3))) void*)s, 16, 0, 0);
}

// ---------------- fp32 -> bf16, all three inputs in one launch -------------
__global__ __launch_bounds__(256) void cvt_all(const float* __restrict__ x,
                                               const float* __restrict__ wq,
                                               const float* __restrict__ wo,
                                               unsigned short* __restrict__ xb,
                                               unsigned short* __restrict__ wqb,
                                               unsigned short* __restrict__ wob) {
  const int bid = blockIdx.x;
  const float* in;
  unsigned short* out;
  int base;
  if (bid < 4096)      { in = x;  out = xb;  base = bid; }
  else if (bid < 7168) { in = wq; out = wqb; base = bid - 4096; }
  else                 { in = wo; out = wob; base = bid - 7168; }
  const int idx = (base * 256 + threadIdx.x) * 4;
  f32x4 v = *(const f32x4*)(in + idx);
  u16x4 r;
  r[0] = f2b(v[0]); r[1] = f2b(v[1]); r[2] = f2b(v[2]); r[3] = f2b(v[3]);
  *(u16x4*)(out + idx) = r;
}

// ---------------- GEMM: C[M,N] = (A[M,K] * W[N,K]^T + bias) * colscale -----
// 128x128 tile, BK=32, dbuf DMA (32KB LDS). V-column blocks (n0>=2048) write
// transposed into vt as packed u16x4. Unchanged from R14.
__global__ __launch_bounds__(256) void gemm_bt(const unsigned short* __restrict__ A,
                                               const unsigned short* __restrict__ W,
                                               const float* __restrict__ bias,
                                               unsigned short* __restrict__ Cb,
                                               unsigned short* __restrict__ vtb,
                                               int M, int N, int K, int qcols) {
  __shared__ unsigned short As[2][128 * 32];
  __shared__ unsigned short Bs[2][128 * 32];
  const int tid  = threadIdx.x;
  const int lane = tid & 63;
  const int w    = tid >> 6;
  const int wy   = w >> 1, wx = w & 1;
  const int l15  = lane & 15, quad = lane >> 4;
  const int xr2  = (l15 >> 1) & 3;
  const int m0 = blockIdx.y * 128, n0 = blockIdx.x * 128;

  const unsigned short* gA[2];
  const unsigned short* gB[2];
  int off[2];
#pragma unroll
  for (int p = 0; p < 2; ++p) {
    const int c = tid + p * 256;
    const int r = c >> 2;
    const int srcc = (c & 3) ^ ((r >> 1) & 3);
    gA[p] = A + (size_t)(m0 + r) * K + srcc * 8;
    gB[p] = W + (size_t)(n0 + r) * K + srcc * 8;
    off[p] = c * 8;
  }

  f32x4 acc[4][4];
#pragma unroll
  for (int i = 0; i < 4; ++i)
#pragma unroll
    for (int j = 0; j < 4; ++j) acc[i][j] = (f32x4){0.f, 0.f, 0.f, 0.f};

#pragma unroll
  for (int p = 0; p < 2; ++p) {
    gl_lds16(gA[p], &As[0][off[p]]);
    gl_lds16(gB[p], &Bs[0][off[p]]);
  }

  const int NIT = K >> 5;
  for (int it = 0; it < NIT; ++it) {
    __syncthreads();
    const int cur = it & 1;
    if (it + 1 < NIT) {
      const int kt = (it + 1) << 5;
#pragma unroll
      for (int p = 0; p < 2; ++p) {
        gl_lds16(gA[p] + kt, &As[cur ^ 1][off[p]]);
        gl_lds16(gB[p] + kt, &Bs[cur ^ 1][off[p]]);
      }
    }
    const unsigned short* Ac = As[cur];
    const unsigned short* Bc = Bs[cur];
    bf16x8 af[4], bfr[4];
#pragma unroll
    for (int i = 0; i < 4; ++i)
      af[i] = *(const bf16x8*)&Ac[(wy * 64 + i * 16 + l15) * 32 + (quad ^ xr2) * 8];
#pragma unroll
    for (int j = 0; j < 4; ++j)
      bfr[j] = *(const bf16x8*)&Bc[(wx * 64 + j * 16 + l15) * 32 + (quad ^ xr2) * 8];
#pragma unroll
    for (int i = 0; i < 4; ++i)
#pragma unroll
      for (int j = 0; j < 4; ++j)
        acc[i][j] = __builtin_amdgcn_mfma_f32_16x16x32_bf16(af[i], bfr[j], acc[i][j], 0, 0, 0);
  }

  const bool vblock = (n0 >= 2048);  // block-uniform
#pragma unroll
  for (int i = 0; i < 4; ++i) {
    const int row = m0 + wy * 64 + i * 16 + quad * 4;
#pragma unroll
    for (int j = 0; j < 4; ++j) {
      const int col = n0 + wx * 64 + j * 16 + l15;
      const float bv = bias[col];
      if (!vblock) {
        const float sc = (col < qcols) ? 0.125f : 1.0f;
#pragma unroll
        for (int r = 0; r < 4; ++r)
          Cb[(size_t)(row + r) * N + col] = f2b((acc[i][j][r] + bv) * sc);
      } else {
        const int hd = col - 2048;
        const int bb = row >> 11, s = row & 2047;
        u16x4 ov;
#pragma unroll
        for (int r = 0; r < 4; ++r) ov[r] = f2b(acc[i][j][r] + bv);
        *(u16x4*)(vtb + ((size_t)(bb * 1024 + hd)) * 2048 + s) = ov;
      }
    }
  }
}

// ---------------- GEMM 64x64 tile, fp32 out (O-projection) -----------------
// Grid 16x64 = 1024 blocks, BK=32 dbuf, 16KB LDS. Unchanged from R11.
__global__ __launch_bounds__(256) void gemm_bt64(const unsigned short* __restrict__ A,
                                                 const unsigned short* __restrict__ W,
                                                 const float* __restrict__ bias,
                                                 float* __restrict__ Cf,
                                                 int M, int N, int K) {
  __shared__ unsigned short As[2][64 * 32];
  __shared__ unsigned short Bs[2][64 * 32];
  const int tid  = threadIdx.x;
  const int lane = tid & 63;
  const int w    = tid >> 6;
  const int wy   = w >> 1, wx = w & 1;
  const int l15  = lane & 15, quad = lane >> 4;
  const int xr2  = (l15 >> 1) & 3;
  const int m0 = blockIdx.y * 64, n0 = blockIdx.x * 64;

  const unsigned short* gA0;
  const unsigned short* gB0;
  int off0;
  {
    const int c = tid;
    const int r = c >> 2;
    const int srcc = (c & 3) ^ ((r >> 1) & 3);
    gA0 = A + (size_t)(m0 + r) * K + srcc * 8;
    gB0 = W + (size_t)(n0 + r) * K + srcc * 8;
    off0 = c * 8;
  }

  f32x4 acc[2][2];
#pragma unroll
  for (int i = 0; i < 2; ++i)
#pragma unroll
    for (int j = 0; j < 2; ++j) acc[i][j] = (f32x4){0.f, 0.f, 0.f, 0.f};

  gl_lds16(gA0, &As[0][off0]);
  gl_lds16(gB0, &Bs[0][off0]);

  const int NIT = K >> 5;
  for (int it = 0; it < NIT; ++it) {
    __syncthreads();
    const int cur = it & 1;
    if (it + 1 < NIT) {
      const int kt = (it + 1) << 5;
      gl_lds16(gA0 + kt, &As[cur ^ 1][off0]);
      gl_lds16(gB0 + kt, &Bs[cur ^ 1][off0]);
    }
    const unsigned short* Ac = As[cur];
    const unsigned short* Bc = Bs[cur];
    bf16x8 af[2], bfr[2];
#pragma unroll
    for (int i = 0; i < 2; ++i)
      af[i] = *(const bf16x8*)&Ac[(wy * 32 + i * 16 + l15) * 32 + (quad ^ xr2) * 8];
#pragma unroll
    for (int j = 0; j < 2; ++j)
      bfr[j] = *(const bf16x8*)&Bc[(wx * 32 + j * 16 + l15) * 32 + (quad ^ xr2) * 8];
#pragma unroll
    for (int i = 0; i < 2; ++i)
#pragma unroll
      for (int j = 0; j < 2; ++j)
        acc[i][j] = __builtin_amdgcn_mfma_f32_16x16x32_bf16(af[i], bfr[j], acc[i][j], 0, 0, 0);
  }

#pragma unroll
  for (int i = 0; i < 2; ++i) {
    const int row = m0 + wy * 32 + i * 16 + quad * 4;
#pragma unroll
    for (int j = 0; j < 2; ++j) {
      const int col = n0 + wx * 32 + j * 16 + l15;
      const float bv = bias[col];
#pragma unroll
      for (int r = 0; r < 4; ++r)
        Cf[(size_t)(row + r) * N + col] = acc[i][j][r] + bv;
    }
  }
}

// ---------------- flash attention v11: split-K across waves ----------------
// Block = 4 waves, ONE 32-q tile; wave w handles kv tiles t = w, w+4, ...
// (disjoint => K/V direct-global frags at exactly 1x redundancy; no main-loop
// barriers — 4 independent chains/block, 12 resident chains/CU). No-max
// softmax => partial O/l sums are order-independent; waves 1-3 dump partials
// to LDS, one barrier, wave 0 reduces + epilogues. Grid (bh 32, qt 64) =
// 2048 blocks, XCD = bh%8, LPT qt = 63-y. LDS: pbuf 9.2KB + red 30.7KB.
__global__ __launch_bounds__(256, 3) void attn_fwd(const unsigned short* __restrict__ qkv,
                                                   const unsigned short* __restrict__ vt,
                                                   unsigned short* __restrict__ o) {
  __shared__ unsigned short pbuf[4][16 * 72];
  __shared__ f32x4 red[3][64][10];   // per lane: 8 acc f32x4 + 1 (l0,l1) ; stride 160B -> 4-way max
  const int tid  = threadIdx.x;
  const int lane = tid & 63;
  const int w    = tid >> 6;
  const int l15  = lane & 15, quad = lane >> 4;
  const int bh = blockIdx.x, b = bh >> 4, h = bh & 15;
  const int qt = 63 - (int)blockIdx.y;  // LPT: heavy q-tiles first
  const int q0 = qt * 32;
  const int T = (qt >> 1) + 1;          // 64-kv tiles covering q0+31

  // Q B-frags: 2 q-subtiles of 16; B[n=q(l15)][k=d(quad*8+j)]
  const unsigned short* qr0 = qkv + (size_t)(b * 2048 + q0 + l15) * 3072 + h * 64;
  const unsigned short* qr1 = qr0 + (size_t)16 * 3072;
  const bf16x8 bq[2][2] = {
    { *(const bf16x8*)(qr0 + quad * 8), *(const bf16x8*)(qr0 + 32 + quad * 8) },
    { *(const bf16x8*)(qr1 + quad * 8), *(const bf16x8*)(qr1 + 32 + quad * 8) } };

  const unsigned short* gK = qkv + (size_t)(b * 2048) * 3072 + 1024 + h * 64;
  const unsigned short* gV = vt + (size_t)(bh * 64) * 2048;

  bf16x8 vones;
#pragma unroll
  for (int k = 0; k < 8; ++k) vones[k] = (short)0x3F80;  // bf16 1.0

  f32x4 acc[2][4];   // O^T partial: col=q(l15), row=d(j*16+quad*4+r)
#pragma unroll
  for (int i = 0; i < 2; ++i)
#pragma unroll
    for (int j = 0; j < 4; ++j) acc[i][j] = (f32x4){0.f, 0.f, 0.f, 0.f};
  f32x4 accL[2] = {(f32x4){0.f, 0.f, 0.f, 0.f}, (f32x4){0.f, 0.f, 0.f, 0.f}};

  unsigned short* P = pbuf[w];

  for (int t = w; t < T; t += 4) {   // disjoint tiles per wave, no barriers
    const int kv0 = t * 64;
    // ---- K A-frags direct from global (1x: each wave a different tile) ----
    bf16x8 kA[4][2];
#pragma unroll
    for (int n = 0; n < 4; ++n) {
      const unsigned short* krow = gK + (size_t)(kv0 + n * 16 + l15) * 3072;
      kA[n][0] = *(const bf16x8*)(krow + quad * 8);
      kA[n][1] = *(const bf16x8*)(krow + 32 + quad * 8);
    }
    // ---- V^T A-frags direct from global (1x) ----
    bf16x8 av[4][2];
#pragma unroll
    for (int j = 0; j < 4; ++j) {
      const unsigned short* vrow = gV + (size_t)(j * 16 + l15) * 2048 + kv0;
      av[j][0] = *(const bf16x8*)(vrow + quad * 8);
      av[j][1] = *(const bf16x8*)(vrow + 32 + quad * 8);
    }
    // ---- per 16-q subtile: S^T -> mask/exp -> P roundtrip -> PV ----
#pragma unroll
    for (int qs = 0; qs < 2; ++qs) {
      f32x4 st[4];
#pragma unroll
      for (int n = 0; n < 4; ++n) {
        f32x4 z = (f32x4){0.f, 0.f, 0.f, 0.f};
        z = __builtin_amdgcn_mfma_f32_16x16x32_bf16(kA[n][0], bq[qs][0], z, 0, 0, 0);
        z = __builtin_amdgcn_mfma_f32_16x16x32_bf16(kA[n][1], bq[qs][1], z, 0, 0, 0);
        st[n] = z;
      }
      const int qbase = q0 + qs * 16;
      if (kv0 + 63 > qbase) {
        const int qrow = qbase + l15;
#pragma unroll
        for (int n = 0; n < 4; ++n)
#pragma unroll
          for (int r = 0; r < 4; ++r)
            if (kv0 + n * 16 + quad * 4 + r > qrow) st[n][r] = -1e30f;
      }
#pragma unroll
      for (int n = 0; n < 4; ++n) {
#pragma unroll
        for (int r = 0; r < 4; ++r) st[n][r] = __expf(st[n][r]);
        u16x4 pw;
        pw[0] = f2b_trunc(st[n][0]); pw[1] = f2b_trunc(st[n][1]);
        pw[2] = f2b_trunc(st[n][2]); pw[3] = f2b_trunc(st[n][3]);
        *(u16x4*)&P[l15 * 72 + n * 16 + quad * 4] = pw;  // in-wave WAR safe
      }
      const bf16x8 bp0 = *(const bf16x8*)&P[l15 * 72 + quad * 8];
      const bf16x8 bp1 = *(const bf16x8*)&P[l15 * 72 + 32 + quad * 8];
      accL[qs] = __builtin_amdgcn_mfma_f32_16x16x32_bf16(vones, bp0, accL[qs], 0, 0, 0);
      accL[qs] = __builtin_amdgcn_mfma_f32_16x16x32_bf16(vones, bp1, accL[qs], 0, 0, 0);
#pragma unroll
      for (int j = 0; j < 4; ++j) {
        acc[qs][j] = __builtin_amdgcn_mfma_f32_16x16x32_bf16(av[j][0], bp0, acc[qs][j], 0, 0, 0);
        acc[qs][j] = __builtin_amdgcn_mfma_f32_16x16x32_bf16(av[j][1], bp1, acc[qs][j], 0, 0, 0);
      }
    }
  }

  // ---- split-K reduction: waves 1-3 dump, barrier, wave 0 sums ----
  if (w > 0) {
    f32x4* dst = red[w - 1][lane];
#pragma unroll
    for (int qs = 0; qs < 2; ++qs)
#pragma unroll
      for (int j = 0; j < 4; ++j) dst[qs * 4 + j] = acc[qs][j];
    dst[8] = (f32x4){accL[0][0], accL[1][0], 0.f, 0.f};
  }
  __syncthreads();
  if (w == 0) {
#pragma unroll
    for (int p = 0; p < 3; ++p) {
      const f32x4* src = red[p][lane];
#pragma unroll
      for (int qs = 0; qs < 2; ++qs)
#pragma unroll
        for (int j = 0; j < 4; ++j) {
          const f32x4 s = src[qs * 4 + j];
#pragma unroll
          for (int r = 0; r < 4; ++r) acc[qs][j][r] += s[r];
        }
      const f32x4 ls = src[8];
      accL[0][0] += ls[0];
      accL[1][0] += ls[1];
    }
    // ---- epilogue: lane holds q=l15, d=j*16+quad*4+r -> packed u16x4 ----
#pragma unroll
    for (int qs = 0; qs < 2; ++qs) {
      const int qrow = q0 + qs * 16 + l15;
      const float inv = 1.0f / accL[qs][0];
      unsigned short* orow = o + (size_t)(b * 2048 + qrow) * 1024 + h * 64;
#pragma unroll
      for (int j = 0; j < 4; ++j) {
        u16x4 ov;
        ov[0] = f2b(acc[qs][j][0] * inv); ov[1] = f2b(acc[qs][j][1] * inv);
        ov[2] = f2b(acc[qs][j][2] * inv); ov[3] = f2b(acc[qs][j][3] * inv);
        *(u16x4*)(orow + j * 16 + quad * 4) = ov;
      }
    }
  }
}

// ---------------------------------------------------------------------------
extern "C" void kernel_launch(void* const* d_in, const int* in_sizes, int n_in,
                              void* d_out, int out_size, void* d_ws, size_t ws_size,
                              hipStream_t stream) {
  const float* x       = (const float*)d_in[0];
  // d_in[1] = mask: causal tril by construction; implemented analytically.
  const float* w_qkv_w = (const float*)d_in[2];
  const float* w_qkv_b = (const float*)d_in[3];
  const float* w_o_w   = (const float*)d_in[4];
  const float* w_o_b   = (const float*)d_in[5];
  float* out = (float*)d_out;

  unsigned short* ws    = (unsigned short*)d_ws;
  unsigned short* xb    = ws;                                  // 4096*1024
  unsigned short* wqb   = xb   + (size_t)4096 * 1024;          // 3072*1024
  unsigned short* wob   = wqb  + (size_t)3072 * 1024;          // 1024*1024
  unsigned short* qkvb  = wob  + (size_t)1024 * 1024;          // 4096*3072
  unsigned short* vtb   = qkvb + (size_t)4096 * 3072;          // 2048*2048
  unsigned short* attnb = vtb  + (size_t)2048 * 2048;          // 4096*1024

  cvt_all<<<8192, 256, 0, stream>>>(x, w_qkv_w, w_o_w, xb, wqb, wob);
  gemm_bt<<<dim3(24, 32), 256, 0, stream>>>(xb, wqb, w_qkv_b, qkvb, vtb, 4096, 3072, 1024, 1024);
  attn_fwd<<<dim3(32, 64), 256, 0, stream>>>(qkvb, vtb, attnb);
  gemm_bt64<<<dim3(16, 64), 256, 0, stream>>>(attnb, wob, w_o_b, out, 4096, 1024, 1024);
}

// Round 16
// 192.141 us; speedup vs baseline: 1.1635x; 1.1635x over previous
//
#include <hip/hip_runtime.h>
#include <cstdint>
#include <cstddef>

// ---------------------------------------------------------------------------
// ChatGPTAttention: x[2,2048,1024] -> QKV proj -> causal MHA (16 heads, dk=64)
//                   -> O proj. bf16 MFMA pipeline, fp32 accumulate.
// Q pre-scaled by 1/8 in QKV-GEMM epilogue; V written transposed by the same
// epilogue (transpose_v eliminated, R14).
// LESSONS: (R5) LDS row stride multiple of 8 ushorts. (R6/R8) XOR swizzle for
// DMA-staged LDS. (R8/R9) dbuf DMA needs occupancy (BK=32). (R11/R15) direct
// global frags: V rows OK at 1x, K rows (6KB stride) serialize — K must be
// LDS-staged. (R12/R13) 1-wave = one latency chain. (R15) split-K dead.
// R16 v12: v7 (the 46us known-good 4-wave structure) with staging switched
// from VGPR round-trip to global_load_lds DMA dbuf + XOR swizzle (the R10
// GEMM recipe): staging leaves the instruction stream, fire-and-forget.
// ---------------------------------------------------------------------------

typedef __attribute__((ext_vector_type(8))) short bf16x8;   // MFMA A/B frag
typedef __attribute__((ext_vector_type(4))) float f32x4;    // MFMA C/D frag
typedef __attribute__((ext_vector_type(4))) unsigned int u32x4;   // 16B copy
typedef __attribute__((ext_vector_type(4))) unsigned short u16x4; // 8B store
typedef __attribute__((ext_vector_type(8))) unsigned short u16x8; // 16B store

__device__ __forceinline__ unsigned short f2b(float f) {  // RNE f32->bf16
  unsigned int u = __float_as_uint(f);
  u = u + 0x7FFFu + ((u >> 16) & 1u);
  return (unsigned short)(u >> 16);
}
__device__ __forceinline__ unsigned short f2b_trunc(float f) {  // truncate
  return (unsigned short)(__float_as_uint(f) >> 16);
}

// async global->LDS DMA, 16B per lane; LDS dest = wave base + lane*16
__device__ __forceinline__ void gl_lds16(const unsigned short* g, unsigned short* s) {
  __builtin_amdgcn_global_load_lds((const __attribute__((address_space(1))) void*)g,
                                   (__attribute__((address_space(3))) void*)s, 16, 0, 0);
}

// ---------------- fp32 -> bf16, all three inputs in one launch -------------
__global__ __launch_bounds__(256) void cvt_all(const float* __restrict__ x,
                                               const float* __restrict__ wq,
                                               const float* __restrict__ wo,
                                               unsigned short* __restrict__ xb,
                                               unsigned short* __restrict__ wqb,
                                               unsigned short* __restrict__ wob) {
  const int bid = blockIdx.x;
  const float* in;
  unsigned short* out;
  int base;
  if (bid < 4096)      { in = x;  out = xb;  base = bid; }
  else if (bid < 7168) { in = wq; out = wqb; base = bid - 4096; }
  else                 { in = wo; out = wob; base = bid - 7168; }
  const int idx = (base * 256 + threadIdx.x) * 4;
  f32x4 v = *(const f32x4*)(in + idx);
  u16x4 r;
  r[0] = f2b(v[0]); r[1] = f2b(v[1]); r[2] = f2b(v[2]); r[3] = f2b(v[3]);
  *(u16x4*)(out + idx) = r;
}

// ---------------- GEMM: C[M,N] = (A[M,K] * W[N,K]^T + bias) * colscale -----
// 128x128 tile, BK=32, dbuf DMA (32KB LDS). V-column blocks (n0>=2048) write
// transposed into vt as packed u16x4. Unchanged from R14.
__global__ __launch_bounds__(256) void gemm_bt(const unsigned short* __restrict__ A,
                                               const unsigned short* __restrict__ W,
                                               const float* __restrict__ bias,
                                               unsigned short* __restrict__ Cb,
                                               unsigned short* __restrict__ vtb,
                                               int M, int N, int K, int qcols) {
  __shared__ unsigned short As[2][128 * 32];
  __shared__ unsigned short Bs[2][128 * 32];
  const int tid  = threadIdx.x;
  const int lane = tid & 63;
  const int w    = tid >> 6;
  const int wy   = w >> 1, wx = w & 1;
  const int l15  = lane & 15, quad = lane >> 4;
  const int xr2  = (l15 >> 1) & 3;
  const int m0 = blockIdx.y * 128, n0 = blockIdx.x * 128;

  const unsigned short* gA[2];
  const unsigned short* gB[2];
  int off[2];
#pragma unroll
  for (int p = 0; p < 2; ++p) {
    const int c = tid + p * 256;
    const int r = c >> 2;
    const int srcc = (c & 3) ^ ((r >> 1) & 3);
    gA[p] = A + (size_t)(m0 + r) * K + srcc * 8;
    gB[p] = W + (size_t)(n0 + r) * K + srcc * 8;
    off[p] = c * 8;
  }

  f32x4 acc[4][4];
#pragma unroll
  for (int i = 0; i < 4; ++i)
#pragma unroll
    for (int j = 0; j < 4; ++j) acc[i][j] = (f32x4){0.f, 0.f, 0.f, 0.f};

#pragma unroll
  for (int p = 0; p < 2; ++p) {
    gl_lds16(gA[p], &As[0][off[p]]);
    gl_lds16(gB[p], &Bs[0][off[p]]);
  }

  const int NIT = K >> 5;
  for (int it = 0; it < NIT; ++it) {
    __syncthreads();
    const int cur = it & 1;
    if (it + 1 < NIT) {
      const int kt = (it + 1) << 5;
#pragma unroll
      for (int p = 0; p < 2; ++p) {
        gl_lds16(gA[p] + kt, &As[cur ^ 1][off[p]]);
        gl_lds16(gB[p] + kt, &Bs[cur ^ 1][off[p]]);
      }
    }
    const unsigned short* Ac = As[cur];
    const unsigned short* Bc = Bs[cur];
    bf16x8 af[4], bfr[4];
#pragma unroll
    for (int i = 0; i < 4; ++i)
      af[i] = *(const bf16x8*)&Ac[(wy * 64 + i * 16 + l15) * 32 + (quad ^ xr2) * 8];
#pragma unroll
    for (int j = 0; j < 4; ++j)
      bfr[j] = *(const bf16x8*)&Bc[(wx * 64 + j * 16 + l15) * 32 + (quad ^ xr2) * 8];
#pragma unroll
    for (int i = 0; i < 4; ++i)
#pragma unroll
      for (int j = 0; j < 4; ++j)
        acc[i][j] = __builtin_amdgcn_mfma_f32_16x16x32_bf16(af[i], bfr[j], acc[i][j], 0, 0, 0);
  }

  const bool vblock = (n0 >= 2048);  // block-uniform
#pragma unroll
  for (int i = 0; i < 4; ++i) {
    const int row = m0 + wy * 64 + i * 16 + quad * 4;
#pragma unroll
    for (int j = 0; j < 4; ++j) {
      const int col = n0 + wx * 64 + j * 16 + l15;
      const float bv = bias[col];
      if (!vblock) {
        const float sc = (col < qcols) ? 0.125f : 1.0f;
#pragma unroll
        for (int r = 0; r < 4; ++r)
          Cb[(size_t)(row + r) * N + col] = f2b((acc[i][j][r] + bv) * sc);
      } else {
        const int hd = col - 2048;
        const int bb = row >> 11, s = row & 2047;
        u16x4 ov;
#pragma unroll
        for (int r = 0; r < 4; ++r) ov[r] = f2b(acc[i][j][r] + bv);
        *(u16x4*)(vtb + ((size_t)(bb * 1024 + hd)) * 2048 + s) = ov;
      }
    }
  }
}

// ---------------- GEMM 64x64 tile, fp32 out (O-projection) -----------------
// Grid 16x64 = 1024 blocks, BK=32 dbuf, 16KB LDS. Unchanged from R11.
__global__ __launch_bounds__(256) void gemm_bt64(const unsigned short* __restrict__ A,
                                                 const unsigned short* __restrict__ W,
                                                 const float* __restrict__ bias,
                                                 float* __restrict__ Cf,
                                                 int M, int N, int K) {
  __shared__ unsigned short As[2][64 * 32];
  __shared__ unsigned short Bs[2][64 * 32];
  const int tid  = threadIdx.x;
  const int lane = tid & 63;
  const int w    = tid >> 6;
  const int wy   = w >> 1, wx = w & 1;
  const int l15  = lane & 15, quad = lane >> 4;
  const int xr2  = (l15 >> 1) & 3;
  const int m0 = blockIdx.y * 64, n0 = blockIdx.x * 64;

  const unsigned short* gA0;
  const unsigned short* gB0;
  int off0;
  {
    const int c = tid;
    const int r = c >> 2;
    const int srcc = (c & 3) ^ ((r >> 1) & 3);
    gA0 = A + (size_t)(m0 + r) * K + srcc * 8;
    gB0 = W + (size_t)(n0 + r) * K + srcc * 8;
    off0 = c * 8;
  }

  f32x4 acc[2][2];
#pragma unroll
  for (int i = 0; i < 2; ++i)
#pragma unroll
    for (int j = 0; j < 2; ++j) acc[i][j] = (f32x4){0.f, 0.f, 0.f, 0.f};

  gl_lds16(gA0, &As[0][off0]);
  gl_lds16(gB0, &Bs[0][off0]);

  const int NIT = K >> 5;
  for (int it = 0; it < NIT; ++it) {
    __syncthreads();
    const int cur = it & 1;
    if (it + 1 < NIT) {
      const int kt = (it + 1) << 5;
      gl_lds16(gA0 + kt, &As[cur ^ 1][off0]);
      gl_lds16(gB0 + kt, &Bs[cur ^ 1][off0]);
    }
    const unsigned short* Ac = As[cur];
    const unsigned short* Bc = Bs[cur];
    bf16x8 af[2], bfr[2];
#pragma unroll
    for (int i = 0; i < 2; ++i)
      af[i] = *(const bf16x8*)&Ac[(wy * 32 + i * 16 + l15) * 32 + (quad ^ xr2) * 8];
#pragma unroll
    for (int j = 0; j < 2; ++j)
      bfr[j] = *(const bf16x8*)&Bc[(wx * 32 + j * 16 + l15) * 32 + (quad ^ xr2) * 8];
#pragma unroll
    for (int i = 0; i < 2; ++i)
#pragma unroll
      for (int j = 0; j < 2; ++j)
        acc[i][j] = __builtin_amdgcn_mfma_f32_16x16x32_bf16(af[i], bfr[j], acc[i][j], 0, 0, 0);
  }

#pragma unroll
  for (int i = 0; i < 2; ++i) {
    const int row = m0 + wy * 32 + i * 16 + quad * 4;
#pragma unroll
    for (int j = 0; j < 2; ++j) {
      const int col = n0 + wx * 32 + j * 16 + l15;
      const float bv = bias[col];
#pragma unroll
      for (int r = 0; r < 4; ++r)
        Cf[(size_t)(row + r) * N + col] = acc[i][j][r] + bv;
    }
  }
}

// ---------------- flash attention v12: v7 + DMA-dbuf staging ---------------
// 4 waves, 32 q/wave (2 subtiles), S^T=KQ^T, O^T=V^T P^T, packed P, LPT,
// XCD=bh%8 — identical to v7 except K/V staged by global_load_lds DMA into
// packed [64][64] XOR-swizzled dbuf LDS (R10 GEMM recipe; v9-verified
// swizzle). Staging leaves the instruction stream entirely. LDS 41.2KB ->
// 3 blocks/CU (same as v7). Grid (bh 32, qt 16).
__global__ __launch_bounds__(256, 3) void attn_fwd(const unsigned short* __restrict__ qkv,
                                                   const unsigned short* __restrict__ vt,
                                                   unsigned short* __restrict__ o) {
  __shared__ unsigned short Ks[2][64 * 64];
  __shared__ unsigned short Vs[2][64 * 64];
  __shared__ unsigned short pbuf[4][16 * 72];
  const int tid  = threadIdx.x;
  const int lane = tid & 63;
  const int w    = tid >> 6;
  const int l15  = lane & 15, quad = lane >> 4;
  const int xr   = l15 & 7;
  const int bh = blockIdx.x, b = bh >> 4, h = bh & 15;
  const int qt = 15 - (int)blockIdx.y;  // LPT order
  const int q0 = qt * 128;
  const int qa = q0 + w * 32;
  const int qb = qa + 16;
  const int T = 2 * qt + 2;

  // DMA staging map: 512 chunks (16B) per 64x64 tile; 2/thread for K, 2 for V.
  // chunk c: row r=c>>3, swizzled source col = ((c&7)^(r&7))*8; LDS dest c*8.
  const unsigned short* gKd[2];
  const unsigned short* gVd[2];
  int doff[2];
#pragma unroll
  for (int p = 0; p < 2; ++p) {
    const int c = tid + p * 256;
    const int r = c >> 3;
    const int sc = ((c & 7) ^ (r & 7)) * 8;
    gKd[p] = qkv + (size_t)(b * 2048 + r) * 3072 + 1024 + h * 64 + sc;
    gVd[p] = vt + (size_t)(bh * 64 + r) * 2048 + sc;
    doff[p] = c * 8;
  }

  const unsigned short* qra = qkv + (size_t)(b * 2048 + qa + l15) * 3072 + h * 64;
  const unsigned short* qrb = qkv + (size_t)(b * 2048 + qb + l15) * 3072 + h * 64;
  const bf16x8 bq[2][2] = {
    { *(const bf16x8*)(qra + quad * 8), *(const bf16x8*)(qra + 32 + quad * 8) },
    { *(const bf16x8*)(qrb + quad * 8), *(const bf16x8*)(qrb + 32 + quad * 8) } };

  bf16x8 vones;
#pragma unroll
  for (int k = 0; k < 8; ++k) vones[k] = (short)0x3F80;  // bf16 1.0

  f32x4 acc[2][4];   // [q-subtile][d-tile] — O^T C-layout: col=q(l15), row=d
#pragma unroll
  for (int i = 0; i < 2; ++i)
#pragma unroll
    for (int j = 0; j < 4; ++j) acc[i][j] = (f32x4){0.f, 0.f, 0.f, 0.f};
  f32x4 accL[2] = {(f32x4){0.f, 0.f, 0.f, 0.f}, (f32x4){0.f, 0.f, 0.f, 0.f}};

  unsigned short* P = pbuf[w];  // [q 0..15][kv 0..63], stride 72

  // prologue: DMA tile 0 -> buf 0
#pragma unroll
  for (int p = 0; p < 2; ++p) {
    gl_lds16(gKd[p], &Ks[0][doff[p]]);
    gl_lds16(gVd[p], &Vs[0][doff[p]]);
  }

  for (int t = 0; t < T; ++t) {
    __syncthreads();  // drains DMA for buf(t&1); other buf's reads done
    const int cur = t & 1;
    // ---- issue DMA for tile t+1 into other buffer ----
    if (t + 1 < T) {
      const size_t ko = (size_t)(t + 1) * 64 * 3072;
      const int vo = (t + 1) * 64;
#pragma unroll
      for (int p = 0; p < 2; ++p) {
        gl_lds16(gKd[p] + ko, &Ks[cur ^ 1][doff[p]]);
        gl_lds16(gVd[p] + vo, &Vs[cur ^ 1][doff[p]]);
      }
    }
    const unsigned short* Kc = Ks[cur];
    const unsigned short* Vc = Vs[cur];
    const int kv0 = t * 64;

    // ---- S^T[kv][q] = K Q^T for both q-subtiles (K frags swizzled) ----
    f32x4 st[2][4];
#pragma unroll
    for (int n = 0; n < 4; ++n) {
      const int row = n * 16 + l15;
      const bf16x8 kA0 = *(const bf16x8*)&Kc[row * 64 + ((quad) ^ xr) * 8];
      const bf16x8 kA1 = *(const bf16x8*)&Kc[row * 64 + ((4 + quad) ^ xr) * 8];
      f32x4 z0 = (f32x4){0.f, 0.f, 0.f, 0.f};
      z0 = __builtin_amdgcn_mfma_f32_16x16x32_bf16(kA0, bq[0][0], z0, 0, 0, 0);
      z0 = __builtin_amdgcn_mfma_f32_16x16x32_bf16(kA1, bq[0][1], z0, 0, 0, 0);
      st[0][n] = z0;
      f32x4 z1 = (f32x4){0.f, 0.f, 0.f, 0.f};
      z1 = __builtin_amdgcn_mfma_f32_16x16x32_bf16(kA0, bq[1][0], z1, 0, 0, 0);
      z1 = __builtin_amdgcn_mfma_f32_16x16x32_bf16(kA1, bq[1][1], z1, 0, 0, 0);
      st[1][n] = z1;
    }
    // ---- V^T A-frags (swizzled LDS reads, shared by both subtiles) ----
    bf16x8 av[4][2];
#pragma unroll
    for (int j = 0; j < 4; ++j) {
      const int row = j * 16 + l15;
      av[j][0] = *(const bf16x8*)&Vc[row * 64 + ((quad) ^ xr) * 8];
      av[j][1] = *(const bf16x8*)&Vc[row * 64 + ((4 + quad) ^ xr) * 8];
    }
    // ---- per q-subtile: mask/exp -> P roundtrip -> PV ----
#pragma unroll
    for (int tq = 0; tq < 2; ++tq) {
      const int qbase = tq ? qb : qa;
      if (kv0 + 63 > qbase) {
        const int qrow = qbase + l15;
#pragma unroll
        for (int n = 0; n < 4; ++n)
#pragma unroll
          for (int r = 0; r < 4; ++r)
            if (kv0 + n * 16 + quad * 4 + r > qrow) st[tq][n][r] = -1e30f;
      }
#pragma unroll
      for (int n = 0; n < 4; ++n) {
#pragma unroll
        for (int r = 0; r < 4; ++r) st[tq][n][r] = __expf(st[tq][n][r]);
        u16x4 pw;
        pw[0] = f2b_trunc(st[tq][n][0]); pw[1] = f2b_trunc(st[tq][n][1]);
        pw[2] = f2b_trunc(st[tq][n][2]); pw[3] = f2b_trunc(st[tq][n][3]);
        *(u16x4*)&P[l15 * 72 + n * 16 + quad * 4] = pw;  // in-wave WAR safe
      }
      const bf16x8 bp0 = *(const bf16x8*)&P[l15 * 72 + quad * 8];
      const bf16x8 bp1 = *(const bf16x8*)&P[l15 * 72 + 32 + quad * 8];
      accL[tq] = __builtin_amdgcn_mfma_f32_16x16x32_bf16(vones, bp0, accL[tq], 0, 0, 0);
      accL[tq] = __builtin_amdgcn_mfma_f32_16x16x32_bf16(vones, bp1, accL[tq], 0, 0, 0);
#pragma unroll
      for (int j = 0; j < 4; ++j) {
        acc[tq][j] = __builtin_amdgcn_mfma_f32_16x16x32_bf16(av[j][0], bp0, acc[tq][j], 0, 0, 0);
        acc[tq][j] = __builtin_amdgcn_mfma_f32_16x16x32_bf16(av[j][1], bp1, acc[tq][j], 0, 0, 0);
      }
    }
  }
  // ---- epilogue: lane holds q=l15, d=j*16+quad*4+r -> packed u16x4 ----
#pragma unroll
  for (int tq = 0; tq < 2; ++tq) {
    const int qrow = (tq ? qb : qa) + l15;
    const float inv = 1.0f / accL[tq][0];  // all rows of accL equal l[q]
    unsigned short* orow = o + (size_t)(b * 2048 + qrow) * 1024 + h * 64;
#pragma unroll
    for (int j = 0; j < 4; ++j) {
      u16x4 ov;
      ov[0] = f2b(acc[tq][j][0] * inv); ov[1] = f2b(acc[tq][j][1] * inv);
      ov[2] = f2b(acc[tq][j][2] * inv); ov[3] = f2b(acc[tq][j][3] * inv);
      *(u16x4*)(orow + j * 16 + quad * 4) = ov;
    }
  }
}

// ---------------------------------------------------------------------------
extern "C" void kernel_launch(void* const* d_in, const int* in_sizes, int n_in,
                              void* d_out, int out_size, void* d_ws, size_t ws_size,
                              hipStream_t stream) {
  const float* x       = (const float*)d_in[0];
  // d_in[1] = mask: causal tril by construction; implemented analytically.
  const float* w_qkv_w = (const float*)d_in[2];
  const float* w_qkv_b = (const float*)d_in[3];
  const float* w_o_w   = (const float*)d_in[4];
  const float* w_o_b   = (const float*)d_in[5];
  float* out = (float*)d_out;

  unsigned short* ws    = (unsigned short*)d_ws;
  unsigned short* xb    = ws;                                  // 4096*1024
  unsigned short* wqb   = xb   + (size_t)4096 * 1024;          // 3072*1024
  unsigned short* wob   = wqb  + (size_t)3072 * 1024;          // 1024*1024
  unsigned short* qkvb  = wob  + (size_t)1024 * 1024;          // 4096*3072
  unsigned short* vtb   = qkvb + (size_t)4096 * 3072;          // 2048*2048
  unsigned short* attnb = vtb  + (size_t)2048 * 2048;          // 4096*1024

  cvt_all<<<8192, 256, 0, stream>>>(x, w_qkv_w, w_o_w, xb, wqb, wob);
  gemm_bt<<<dim3(24, 32), 256, 0, stream>>>(xb, wqb, w_qkv_b, qkvb, vtb, 4096, 3072, 1024, 1024);
  attn_fwd<<<dim3(32, 16), 256, 0, stream>>>(qkvb, vtb, attnb);
  gemm_bt64<<<dim3(16, 64), 256, 0, stream>>>(attnb, wob, w_o_b, out, 4096, 1024, 1024);
}

// Round 17
// 186.994 us; speedup vs baseline: 1.1956x; 1.0275x over previous
//
#include <hip/hip_runtime.h>
#include <cstdint>
#include <cstddef>

// ---------------------------------------------------------------------------
// ChatGPTAttention: x[2,2048,1024] -> QKV proj -> causal MHA (16 heads, dk=64)
//                   -> O proj. bf16 MFMA pipeline, fp32 accumulate.
// Q pre-scaled by 1/8 in QKV-GEMM epilogue; V written transposed by the same
// epilogue (transpose_v eliminated, R14).
// LESSONS: (R5) LDS row stride multiple of 8 ushorts. (R6/R8) XOR swizzle for
// DMA-staged LDS. (R8/R9) dbuf DMA needs occupancy preserved. (R11/R15)
// direct global frags: V rows OK at 1x, K rows serialize — stage K. (R12/R13)
// 1-wave = one latency chain. (R15) split-K dead. (R16) DMA dbuf staging in
// attn: 46.4->44.6, conflicts 3.9M->1.67M, but grid 512 = 2 blocks/CU cap.
// R17: attn v13 = v12 with 2-wave/64-q blocks -> grid 1024 = 4 blocks/CU
// (LDS 36.6KB); gemm_bt64 BK 32->64 (dbuf, 32KB, still 4/CU) — halves
// barrier drains on the worst MFMA:drain-ratio kernel.
// ---------------------------------------------------------------------------

typedef __attribute__((ext_vector_type(8))) short bf16x8;   // MFMA A/B frag
typedef __attribute__((ext_vector_type(4))) float f32x4;    // MFMA C/D frag
typedef __attribute__((ext_vector_type(4))) unsigned int u32x4;   // 16B copy
typedef __attribute__((ext_vector_type(4))) unsigned short u16x4; // 8B store
typedef __attribute__((ext_vector_type(8))) unsigned short u16x8; // 16B store

__device__ __forceinline__ unsigned short f2b(float f) {  // RNE f32->bf16
  unsigned int u = __float_as_uint(f);
  u = u + 0x7FFFu + ((u >> 16) & 1u);
  return (unsigned short)(u >> 16);
}
__device__ __forceinline__ unsigned short f2b_trunc(float f) {  // truncate
  return (unsigned short)(__float_as_uint(f) >> 16);
}

// async global->LDS DMA, 16B per lane; LDS dest = wave base + lane*16
__device__ __forceinline__ void gl_lds16(const unsigned short* g, unsigned short* s) {
  __builtin_amdgcn_global_load_lds((const __attribute__((address_space(1))) void*)g,
                                   (__attribute__((address_space(3))) void*)s, 16, 0, 0);
}

// ---------------- fp32 -> bf16, all three inputs in one launch -------------
__global__ __launch_bounds__(256) void cvt_all(const float* __restrict__ x,
                                               const float* __restrict__ wq,
                                               const float* __restrict__ wo,
                                               unsigned short* __restrict__ xb,
                                               unsigned short* __restrict__ wqb,
                                               unsigned short* __restrict__ wob) {
  const int bid = blockIdx.x;
  const float* in;
  unsigned short* out;
  int base;
  if (bid < 4096)      { in = x;  out = xb;  base = bid; }
  else if (bid < 7168) { in = wq; out = wqb; base = bid - 4096; }
  else                 { in = wo; out = wob; base = bid - 7168; }
  const int idx = (base * 256 + threadIdx.x) * 4;
  f32x4 v = *(const f32x4*)(in + idx);
  u16x4 r;
  r[0] = f2b(v[0]); r[1] = f2b(v[1]); r[2] = f2b(v[2]); r[3] = f2b(v[3]);
  *(u16x4*)(out + idx) = r;
}

// ---------------- GEMM: C[M,N] = (A[M,K] * W[N,K]^T + bias) * colscale -----
// 128x128 tile, BK=32, dbuf DMA (32KB LDS). V-column blocks (n0>=2048) write
// transposed into vt as packed u16x4. Unchanged from R14.
__global__ __launch_bounds__(256) void gemm_bt(const unsigned short* __restrict__ A,
                                               const unsigned short* __restrict__ W,
                                               const float* __restrict__ bias,
                                               unsigned short* __restrict__ Cb,
                                               unsigned short* __restrict__ vtb,
                                               int M, int N, int K, int qcols) {
  __shared__ unsigned short As[2][128 * 32];
  __shared__ unsigned short Bs[2][128 * 32];
  const int tid  = threadIdx.x;
  const int lane = tid & 63;
  const int w    = tid >> 6;
  const int wy   = w >> 1, wx = w & 1;
  const int l15  = lane & 15, quad = lane >> 4;
  const int xr2  = (l15 >> 1) & 3;
  const int m0 = blockIdx.y * 128, n0 = blockIdx.x * 128;

  const unsigned short* gA[2];
  const unsigned short* gB[2];
  int off[2];
#pragma unroll
  for (int p = 0; p < 2; ++p) {
    const int c = tid + p * 256;
    const int r = c >> 2;
    const int srcc = (c & 3) ^ ((r >> 1) & 3);
    gA[p] = A + (size_t)(m0 + r) * K + srcc * 8;
    gB[p] = W + (size_t)(n0 + r) * K + srcc * 8;
    off[p] = c * 8;
  }

  f32x4 acc[4][4];
#pragma unroll
  for (int i = 0; i < 4; ++i)
#pragma unroll
    for (int j = 0; j < 4; ++j) acc[i][j] = (f32x4){0.f, 0.f, 0.f, 0.f};

#pragma unroll
  for (int p = 0; p < 2; ++p) {
    gl_lds16(gA[p], &As[0][off[p]]);
    gl_lds16(gB[p], &Bs[0][off[p]]);
  }

  const int NIT = K >> 5;
  for (int it = 0; it < NIT; ++it) {
    __syncthreads();
    const int cur = it & 1;
    if (it + 1 < NIT) {
      const int kt = (it + 1) << 5;
#pragma unroll
      for (int p = 0; p < 2; ++p) {
        gl_lds16(gA[p] + kt, &As[cur ^ 1][off[p]]);
        gl_lds16(gB[p] + kt, &Bs[cur ^ 1][off[p]]);
      }
    }
    const unsigned short* Ac = As[cur];
    const unsigned short* Bc = Bs[cur];
    bf16x8 af[4], bfr[4];
#pragma unroll
    for (int i = 0; i < 4; ++i)
      af[i] = *(const bf16x8*)&Ac[(wy * 64 + i * 16 + l15) * 32 + (quad ^ xr2) * 8];
#pragma unroll
    for (int j = 0; j < 4; ++j)
      bfr[j] = *(const bf16x8*)&Bc[(wx * 64 + j * 16 + l15) * 32 + (quad ^ xr2) * 8];
#pragma unroll
    for (int i = 0; i < 4; ++i)
#pragma unroll
      for (int j = 0; j < 4; ++j)
        acc[i][j] = __builtin_amdgcn_mfma_f32_16x16x32_bf16(af[i], bfr[j], acc[i][j], 0, 0, 0);
  }

  const bool vblock = (n0 >= 2048);  // block-uniform
#pragma unroll
  for (int i = 0; i < 4; ++i) {
    const int row = m0 + wy * 64 + i * 16 + quad * 4;
#pragma unroll
    for (int j = 0; j < 4; ++j) {
      const int col = n0 + wx * 64 + j * 16 + l15;
      const float bv = bias[col];
      if (!vblock) {
        const float sc = (col < qcols) ? 0.125f : 1.0f;
#pragma unroll
        for (int r = 0; r < 4; ++r)
          Cb[(size_t)(row + r) * N + col] = f2b((acc[i][j][r] + bv) * sc);
      } else {
        const int hd = col - 2048;
        const int bb = row >> 11, s = row & 2047;
        u16x4 ov;
#pragma unroll
        for (int r = 0; r < 4; ++r) ov[r] = f2b(acc[i][j][r] + bv);
        *(u16x4*)(vtb + ((size_t)(bb * 1024 + hd)) * 2048 + s) = ov;
      }
    }
  }
}

// ---------------- GEMM 64x64 tile, fp32 out (O-projection) -----------------
// Grid 16x64 = 1024 blocks. R17: BK=64 dbuf (32KB LDS, still 4 blocks/CU) —
// 16 barrier-drains instead of 32, 8 MFMA per drain instead of 4.
__global__ __launch_bounds__(256) void gemm_bt64(const unsigned short* __restrict__ A,
                                                 const unsigned short* __restrict__ W,
                                                 const float* __restrict__ bias,
                                                 float* __restrict__ Cf,
                                                 int M, int N, int K) {
  __shared__ unsigned short As[2][64 * 64];
  __shared__ unsigned short Bs[2][64 * 64];
  const int tid  = threadIdx.x;
  const int lane = tid & 63;
  const int w    = tid >> 6;
  const int wy   = w >> 1, wx = w & 1;
  const int l15  = lane & 15, quad = lane >> 4;
  const int xr   = l15 & 7;
  const int m0 = blockIdx.y * 64, n0 = blockIdx.x * 64;

  // 512 16B-chunks per 64x64 tile; 2/thread per array. Swizzle: row r=c>>3,
  // source col = ((c&7)^(r&7))*8; LDS dest = c*8.
  const unsigned short* gA[2];
  const unsigned short* gB[2];
  int off[2];
#pragma unroll
  for (int p = 0; p < 2; ++p) {
    const int c = tid + p * 256;
    const int r = c >> 3;
    const int sc = ((c & 7) ^ (r & 7)) * 8;
    gA[p] = A + (size_t)(m0 + r) * K + sc;
    gB[p] = W + (size_t)(n0 + r) * K + sc;
    off[p] = c * 8;
  }

  f32x4 acc[2][2];
#pragma unroll
  for (int i = 0; i < 2; ++i)
#pragma unroll
    for (int j = 0; j < 2; ++j) acc[i][j] = (f32x4){0.f, 0.f, 0.f, 0.f};

#pragma unroll
  for (int p = 0; p < 2; ++p) {
    gl_lds16(gA[p], &As[0][off[p]]);
    gl_lds16(gB[p], &Bs[0][off[p]]);
  }

  const int NIT = K >> 6;
  for (int it = 0; it < NIT; ++it) {
    __syncthreads();
    const int cur = it & 1;
    if (it + 1 < NIT) {
      const int kt = (it + 1) << 6;
#pragma unroll
      for (int p = 0; p < 2; ++p) {
        gl_lds16(gA[p] + kt, &As[cur ^ 1][off[p]]);
        gl_lds16(gB[p] + kt, &Bs[cur ^ 1][off[p]]);
      }
    }
    const unsigned short* Ac = As[cur];
    const unsigned short* Bc = Bs[cur];
#pragma unroll
    for (int kc = 0; kc < 2; ++kc) {
      bf16x8 af[2], bfr[2];
#pragma unroll
      for (int i = 0; i < 2; ++i)
        af[i] = *(const bf16x8*)&Ac[(wy * 32 + i * 16 + l15) * 64 + ((kc * 4 + quad) ^ xr) * 8];
#pragma unroll
      for (int j = 0; j < 2; ++j)
        bfr[j] = *(const bf16x8*)&Bc[(wx * 32 + j * 16 + l15) * 64 + ((kc * 4 + quad) ^ xr) * 8];
#pragma unroll
      for (int i = 0; i < 2; ++i)
#pragma unroll
        for (int j = 0; j < 2; ++j)
          acc[i][j] = __builtin_amdgcn_mfma_f32_16x16x32_bf16(af[i], bfr[j], acc[i][j], 0, 0, 0);
    }
  }

#pragma unroll
  for (int i = 0; i < 2; ++i) {
    const int row = m0 + wy * 32 + i * 16 + quad * 4;
#pragma unroll
    for (int j = 0; j < 2; ++j) {
      const int col = n0 + wx * 32 + j * 16 + l15;
      const float bv = bias[col];
#pragma unroll
      for (int r = 0; r < 4; ++r)
        Cf[(size_t)(row + r) * N + col] = acc[i][j][r] + bv;
    }
  }
}

// ---------------- flash attention v13: v12 with 2-wave/64-q blocks ---------
// Block = 2 waves x 32 q = 64 q; grid (bh 32, qt 32) = 1024 blocks = 4
// blocks/CU (LDS 36.6KB: Ks/Vs dbuf 32KB + pbuf 4.6KB). Same v12 internals:
// DMA dbuf XOR-swizzled K/V staging, S^T=KQ^T, O^T=V^T P^T, packed P,
// no-max softmax, l via ones-A MFMA, LPT qt=31-y, XCD=bh%8.
__global__ __launch_bounds__(128, 2) void attn_fwd(const unsigned short* __restrict__ qkv,
                                                   const unsigned short* __restrict__ vt,
                                                   unsigned short* __restrict__ o) {
  __shared__ unsigned short Ks[2][64 * 64];
  __shared__ unsigned short Vs[2][64 * 64];
  __shared__ unsigned short pbuf[2][16 * 72];
  const int tid  = threadIdx.x;
  const int lane = tid & 63;
  const int w    = tid >> 6;          // 2 waves
  const int l15  = lane & 15, quad = lane >> 4;
  const int xr   = l15 & 7;
  const int bh = blockIdx.x, b = bh >> 4, h = bh & 15;
  const int qt = 31 - (int)blockIdx.y;  // LPT order (64-q tiles)
  const int q0 = qt * 64;
  const int qa = q0 + w * 32;
  const int qb = qa + 16;
  const int T = qt + 1;

  // DMA staging: 512 chunks per 64x64 tile / 128 threads = 4/thread/array.
  const unsigned short* gKd[4];
  const unsigned short* gVd[4];
  int doff[4];
#pragma unroll
  for (int p = 0; p < 4; ++p) {
    const int c = tid + p * 128;
    const int r = c >> 3;
    const int sc = ((c & 7) ^ (r & 7)) * 8;
    gKd[p] = qkv + (size_t)(b * 2048 + r) * 3072 + 1024 + h * 64 + sc;
    gVd[p] = vt + (size_t)(bh * 64 + r) * 2048 + sc;
    doff[p] = c * 8;
  }

  const unsigned short* qra = qkv + (size_t)(b * 2048 + qa + l15) * 3072 + h * 64;
  const unsigned short* qrb = qkv + (size_t)(b * 2048 + qb + l15) * 3072 + h * 64;
  const bf16x8 bq[2][2] = {
    { *(const bf16x8*)(qra + quad * 8), *(const bf16x8*)(qra + 32 + quad * 8) },
    { *(const bf16x8*)(qrb + quad * 8), *(const bf16x8*)(qrb + 32 + quad * 8) } };

  bf16x8 vones;
#pragma unroll
  for (int k = 0; k < 8; ++k) vones[k] = (short)0x3F80;  // bf16 1.0

  f32x4 acc[2][4];   // [q-subtile][d-tile] — O^T C-layout: col=q(l15), row=d
#pragma unroll
  for (int i = 0; i < 2; ++i)
#pragma unroll
    for (int j = 0; j < 4; ++j) acc[i][j] = (f32x4){0.f, 0.f, 0.f, 0.f};
  f32x4 accL[2] = {(f32x4){0.f, 0.f, 0.f, 0.f}, (f32x4){0.f, 0.f, 0.f, 0.f}};

  unsigned short* P = pbuf[w];  // [q 0..15][kv 0..63], stride 72

  // prologue: DMA tile 0 -> buf 0
#pragma unroll
  for (int p = 0; p < 4; ++p) {
    gl_lds16(gKd[p], &Ks[0][doff[p]]);
    gl_lds16(gVd[p], &Vs[0][doff[p]]);
  }

  for (int t = 0; t < T; ++t) {
    __syncthreads();  // drains DMA for buf(t&1); other buf's reads done
    const int cur = t & 1;
    if (t + 1 < T) {
      const size_t ko = (size_t)(t + 1) * 64 * 3072;
      const int vo = (t + 1) * 64;
#pragma unroll
      for (int p = 0; p < 4; ++p) {
        gl_lds16(gKd[p] + ko, &Ks[cur ^ 1][doff[p]]);
        gl_lds16(gVd[p] + vo, &Vs[cur ^ 1][doff[p]]);
      }
    }
    const unsigned short* Kc = Ks[cur];
    const unsigned short* Vc = Vs[cur];
    const int kv0 = t * 64;

    // ---- S^T[kv][q] = K Q^T for both q-subtiles (K frags swizzled) ----
    f32x4 st[2][4];
#pragma unroll
    for (int n = 0; n < 4; ++n) {
      const int row = n * 16 + l15;
      const bf16x8 kA0 = *(const bf16x8*)&Kc[row * 64 + ((quad) ^ xr) * 8];
      const bf16x8 kA1 = *(const bf16x8*)&Kc[row * 64 + ((4 + quad) ^ xr) * 8];
      f32x4 z0 = (f32x4){0.f, 0.f, 0.f, 0.f};
      z0 = __builtin_amdgcn_mfma_f32_16x16x32_bf16(kA0, bq[0][0], z0, 0, 0, 0);
      z0 = __builtin_amdgcn_mfma_f32_16x16x32_bf16(kA1, bq[0][1], z0, 0, 0, 0);
      st[0][n] = z0;
      f32x4 z1 = (f32x4){0.f, 0.f, 0.f, 0.f};
      z1 = __builtin_amdgcn_mfma_f32_16x16x32_bf16(kA0, bq[1][0], z1, 0, 0, 0);
      z1 = __builtin_amdgcn_mfma_f32_16x16x32_bf16(kA1, bq[1][1], z1, 0, 0, 0);
      st[1][n] = z1;
    }
    // ---- V^T A-frags (swizzled LDS reads, shared by both subtiles) ----
    bf16x8 av[4][2];
#pragma unroll
    for (int j = 0; j < 4; ++j) {
      const int row = j * 16 + l15;
      av[j][0] = *(const bf16x8*)&Vc[row * 64 + ((quad) ^ xr) * 8];
      av[j][1] = *(const bf16x8*)&Vc[row * 64 + ((4 + quad) ^ xr) * 8];
    }
    // ---- per q-subtile: mask/exp -> P roundtrip -> PV ----
#pragma unroll
    for (int tq = 0; tq < 2; ++tq) {
      const int qbase = tq ? qb : qa;
      if (kv0 + 63 > qbase) {
        const int qrow = qbase + l15;
#pragma unroll
        for (int n = 0; n < 4; ++n)
#pragma unroll
          for (int r = 0; r < 4; ++r)
            if (kv0 + n * 16 + quad * 4 + r > qrow) st[tq][n][r] = -1e30f;
      }
#pragma unroll
      for (int n = 0; n < 4; ++n) {
#pragma unroll
        for (int r = 0; r < 4; ++r) st[tq][n][r] = __expf(st[tq][n][r]);
        u16x4 pw;
        pw[0] = f2b_trunc(st[tq][n][0]); pw[1] = f2b_trunc(st[tq][n][1]);
        pw[2] = f2b_trunc(st[tq][n][2]); pw[3] = f2b_trunc(st[tq][n][3]);
        *(u16x4*)&P[l15 * 72 + n * 16 + quad * 4] = pw;  // in-wave WAR safe
      }
      const bf16x8 bp0 = *(const bf16x8*)&P[l15 * 72 + quad * 8];
      const bf16x8 bp1 = *(const bf16x8*)&P[l15 * 72 + 32 + quad * 8];
      accL[tq] = __builtin_amdgcn_mfma_f32_16x16x32_bf16(vones, bp0, accL[tq], 0, 0, 0);
      accL[tq] = __builtin_amdgcn_mfma_f32_16x16x32_bf16(vones, bp1, accL[tq], 0, 0, 0);
#pragma unroll
      for (int j = 0; j < 4; ++j) {
        acc[tq][j] = __builtin_amdgcn_mfma_f32_16x16x32_bf16(av[j][0], bp0, acc[tq][j], 0, 0, 0);
        acc[tq][j] = __builtin_amdgcn_mfma_f32_16x16x32_bf16(av[j][1], bp1, acc[tq][j], 0, 0, 0);
      }
    }
  }
  // ---- epilogue: lane holds q=l15, d=j*16+quad*4+r -> packed u16x4 ----
#pragma unroll
  for (int tq = 0; tq < 2; ++tq) {
    const int qrow = (tq ? qb : qa) + l15;
    const float inv = 1.0f / accL[tq][0];  // all rows of accL equal l[q]
    unsigned short* orow = o + (size_t)(b * 2048 + qrow) * 1024 + h * 64;
#pragma unroll
    for (int j = 0; j < 4; ++j) {
      u16x4 ov;
      ov[0] = f2b(acc[tq][j][0] * inv); ov[1] = f2b(acc[tq][j][1] * inv);
      ov[2] = f2b(acc[tq][j][2] * inv); ov[3] = f2b(acc[tq][j][3] * inv);
      *(u16x4*)(orow + j * 16 + quad * 4) = ov;
    }
  }
}

// ---------------------------------------------------------------------------
extern "C" void kernel_launch(void* const* d_in, const int* in_sizes, int n_in,
                              void* d_out, int out_size, void* d_ws, size_t ws_size,
                              hipStream_t stream) {
  const float* x       = (const float*)d_in[0];
  // d_in[1] = mask: causal tril by construction; implemented analytically.
  const float* w_qkv_w = (const float*)d_in[2];
  const float* w_qkv_b = (const float*)d_in[3];
  const float* w_o_w   = (const float*)d_in[4];
  const float* w_o_b   = (const float*)d_in[5];
  float* out = (float*)d_out;

  unsigned short* ws    = (unsigned short*)d_ws;
  unsigned short* xb    = ws;                                  // 4096*1024
  unsigned short* wqb   = xb   + (size_t)4096 * 1024;          // 3072*1024
  unsigned short* wob   = wqb  + (size_t)3072 * 1024;          // 1024*1024
  unsigned short* qkvb  = wob  + (size_t)1024 * 1024;          // 4096*3072
  unsigned short* vtb   = qkvb + (size_t)4096 * 3072;          // 2048*2048
  unsigned short* attnb = vtb  + (size_t)2048 * 2048;          // 4096*1024

  cvt_all<<<8192, 256, 0, stream>>>(x, w_qkv_w, w_o_w, xb, wqb, wob);
  gemm_bt<<<dim3(24, 32), 256, 0, stream>>>(xb, wqb, w_qkv_b, qkvb, vtb, 4096, 3072, 1024, 1024);
  attn_fwd<<<dim3(32, 32), 128, 0, stream>>>(qkvb, vtb, attnb);
  gemm_bt64<<<dim3(16, 64), 256, 0, stream>>>(attnb, wob, w_o_b, out, 4096, 1024, 1024);
}

// Round 18
// 185.518 us; speedup vs baseline: 1.2051x; 1.0080x over previous
//
#include <hip/hip_runtime.h>
#include <cstdint>
#include <cstddef>

// ---------------------------------------------------------------------------
// ChatGPTAttention: x[2,2048,1024] -> QKV proj -> causal MHA (16 heads, dk=64)
//                   -> O proj. bf16 MFMA pipeline, fp32 accumulate.
// Q pre-scaled by 1/8 in QKV-GEMM epilogue; V written transposed by the same
// epilogue (transpose_v eliminated, R14).
// LESSONS: (R5) LDS row stride multiple of 8 ushorts. (R6/R8) XOR swizzle for
// DMA-staged LDS. (R8/R9) dbuf DMA needs occupancy preserved. (R11/R15)
// direct global frags: V rows OK at 1x, K rows serialize — stage K. (R12/R13)
// 1-wave = one latency chain. (R15) split-K dead. (R16/R17 A/B) attn dur
// identical at 2 vs 4 blocks/CU -> occupancy NOT binding; in-wave chain is.
// R18 v14: split P buffer per q-subtile (removes the Pw(tq1)-after-Pr(tq0)
// same-address WAR serialization, ~150-300 cyc/trip of critical path);
// reorder to exp0,Pw0,exp1,Pw1,Pr0,PV0,Pr1,PV1. LDS 41.2KB -> 3/CU (proven
// non-binding). GEMMs/cvt unchanged from R17 (best total 187.0).
// ---------------------------------------------------------------------------

typedef __attribute__((ext_vector_type(8))) short bf16x8;   // MFMA A/B frag
typedef __attribute__((ext_vector_type(4))) float f32x4;    // MFMA C/D frag
typedef __attribute__((ext_vector_type(4))) unsigned int u32x4;   // 16B copy
typedef __attribute__((ext_vector_type(4))) unsigned short u16x4; // 8B store
typedef __attribute__((ext_vector_type(8))) unsigned short u16x8; // 16B store

__device__ __forceinline__ unsigned short f2b(float f) {  // RNE f32->bf16
  unsigned int u = __float_as_uint(f);
  u = u + 0x7FFFu + ((u >> 16) & 1u);
  return (unsigned short)(u >> 16);
}
__device__ __forceinline__ unsigned short f2b_trunc(float f) {  // truncate
  return (unsigned short)(__float_as_uint(f) >> 16);
}

// async global->LDS DMA, 16B per lane; LDS dest = wave base + lane*16
__device__ __forceinline__ void gl_lds16(const unsigned short* g, unsigned short* s) {
  __builtin_amdgcn_global_load_lds((const __attribute__((address_space(1))) void*)g,
                                   (__attribute__((address_space(3))) void*)s, 16, 0, 0);
}

// ---------------- fp32 -> bf16, all three inputs in one launch -------------
__global__ __launch_bounds__(256) void cvt_all(const float* __restrict__ x,
                                               const float* __restrict__ wq,
                                               const float* __restrict__ wo,
                                               unsigned short* __restrict__ xb,
                                               unsigned short* __restrict__ wqb,
                                               unsigned short* __restrict__ wob) {
  const int bid = blockIdx.x;
  const float* in;
  unsigned short* out;
  int base;
  if (bid < 4096)      { in = x;  out = xb;  base = bid; }
  else if (bid < 7168) { in = wq; out = wqb; base = bid - 4096; }
  else                 { in = wo; out = wob; base = bid - 7168; }
  const int idx = (base * 256 + threadIdx.x) * 4;
  f32x4 v = *(const f32x4*)(in + idx);
  u16x4 r;
  r[0] = f2b(v[0]); r[1] = f2b(v[1]); r[2] = f2b(v[2]); r[3] = f2b(v[3]);
  *(u16x4*)(out + idx) = r;
}

// ---------------- GEMM: C[M,N] = (A[M,K] * W[N,K]^T + bias) * colscale -----
// 128x128 tile, BK=32, dbuf DMA (32KB LDS). V-column blocks (n0>=2048) write
// transposed into vt as packed u16x4. Unchanged from R14.
__global__ __launch_bounds__(256) void gemm_bt(const unsigned short* __restrict__ A,
                                               const unsigned short* __restrict__ W,
                                               const float* __restrict__ bias,
                                               unsigned short* __restrict__ Cb,
                                               unsigned short* __restrict__ vtb,
                                               int M, int N, int K, int qcols) {
  __shared__ unsigned short As[2][128 * 32];
  __shared__ unsigned short Bs[2][128 * 32];
  const int tid  = threadIdx.x;
  const int lane = tid & 63;
  const int w    = tid >> 6;
  const int wy   = w >> 1, wx = w & 1;
  const int l15  = lane & 15, quad = lane >> 4;
  const int xr2  = (l15 >> 1) & 3;
  const int m0 = blockIdx.y * 128, n0 = blockIdx.x * 128;

  const unsigned short* gA[2];
  const unsigned short* gB[2];
  int off[2];
#pragma unroll
  for (int p = 0; p < 2; ++p) {
    const int c = tid + p * 256;
    const int r = c >> 2;
    const int srcc = (c & 3) ^ ((r >> 1) & 3);
    gA[p] = A + (size_t)(m0 + r) * K + srcc * 8;
    gB[p] = W + (size_t)(n0 + r) * K + srcc * 8;
    off[p] = c * 8;
  }

  f32x4 acc[4][4];
#pragma unroll
  for (int i = 0; i < 4; ++i)
#pragma unroll
    for (int j = 0; j < 4; ++j) acc[i][j] = (f32x4){0.f, 0.f, 0.f, 0.f};

#pragma unroll
  for (int p = 0; p < 2; ++p) {
    gl_lds16(gA[p], &As[0][off[p]]);
    gl_lds16(gB[p], &Bs[0][off[p]]);
  }

  const int NIT = K >> 5;
  for (int it = 0; it < NIT; ++it) {
    __syncthreads();
    const int cur = it & 1;
    if (it + 1 < NIT) {
      const int kt = (it + 1) << 5;
#pragma unroll
      for (int p = 0; p < 2; ++p) {
        gl_lds16(gA[p] + kt, &As[cur ^ 1][off[p]]);
        gl_lds16(gB[p] + kt, &Bs[cur ^ 1][off[p]]);
      }
    }
    const unsigned short* Ac = As[cur];
    const unsigned short* Bc = Bs[cur];
    bf16x8 af[4], bfr[4];
#pragma unroll
    for (int i = 0; i < 4; ++i)
      af[i] = *(const bf16x8*)&Ac[(wy * 64 + i * 16 + l15) * 32 + (quad ^ xr2) * 8];
#pragma unroll
    for (int j = 0; j < 4; ++j)
      bfr[j] = *(const bf16x8*)&Bc[(wx * 64 + j * 16 + l15) * 32 + (quad ^ xr2) * 8];
#pragma unroll
    for (int i = 0; i < 4; ++i)
#pragma unroll
      for (int j = 0; j < 4; ++j)
        acc[i][j] = __builtin_amdgcn_mfma_f32_16x16x32_bf16(af[i], bfr[j], acc[i][j], 0, 0, 0);
  }

  const bool vblock = (n0 >= 2048);  // block-uniform
#pragma unroll
  for (int i = 0; i < 4; ++i) {
    const int row = m0 + wy * 64 + i * 16 + quad * 4;
#pragma unroll
    for (int j = 0; j < 4; ++j) {
      const int col = n0 + wx * 64 + j * 16 + l15;
      const float bv = bias[col];
      if (!vblock) {
        const float sc = (col < qcols) ? 0.125f : 1.0f;
#pragma unroll
        for (int r = 0; r < 4; ++r)
          Cb[(size_t)(row + r) * N + col] = f2b((acc[i][j][r] + bv) * sc);
      } else {
        const int hd = col - 2048;
        const int bb = row >> 11, s = row & 2047;
        u16x4 ov;
#pragma unroll
        for (int r = 0; r < 4; ++r) ov[r] = f2b(acc[i][j][r] + bv);
        *(u16x4*)(vtb + ((size_t)(bb * 1024 + hd)) * 2048 + s) = ov;
      }
    }
  }
}

// ---------------- GEMM 64x64 tile, fp32 out (O-projection) -----------------
// Grid 16x64 = 1024 blocks. BK=64 dbuf (32KB LDS, 4 blocks/CU). R17 config.
__global__ __launch_bounds__(256) void gemm_bt64(const unsigned short* __restrict__ A,
                                                 const unsigned short* __restrict__ W,
                                                 const float* __restrict__ bias,
                                                 float* __restrict__ Cf,
                                                 int M, int N, int K) {
  __shared__ unsigned short As[2][64 * 64];
  __shared__ unsigned short Bs[2][64 * 64];
  const int tid  = threadIdx.x;
  const int lane = tid & 63;
  const int w    = tid >> 6;
  const int wy   = w >> 1, wx = w & 1;
  const int l15  = lane & 15, quad = lane >> 4;
  const int xr   = l15 & 7;
  const int m0 = blockIdx.y * 64, n0 = blockIdx.x * 64;

  const unsigned short* gA[2];
  const unsigned short* gB[2];
  int off[2];
#pragma unroll
  for (int p = 0; p < 2; ++p) {
    const int c = tid + p * 256;
    const int r = c >> 3;
    const int sc = ((c & 7) ^ (r & 7)) * 8;
    gA[p] = A + (size_t)(m0 + r) * K + sc;
    gB[p] = W + (size_t)(n0 + r) * K + sc;
    off[p] = c * 8;
  }

  f32x4 acc[2][2];
#pragma unroll
  for (int i = 0; i < 2; ++i)
#pragma unroll
    for (int j = 0; j < 2; ++j) acc[i][j] = (f32x4){0.f, 0.f, 0.f, 0.f};

#pragma unroll
  for (int p = 0; p < 2; ++p) {
    gl_lds16(gA[p], &As[0][off[p]]);
    gl_lds16(gB[p], &Bs[0][off[p]]);
  }

  const int NIT = K >> 6;
  for (int it = 0; it < NIT; ++it) {
    __syncthreads();
    const int cur = it & 1;
    if (it + 1 < NIT) {
      const int kt = (it + 1) << 6;
#pragma unroll
      for (int p = 0; p < 2; ++p) {
        gl_lds16(gA[p] + kt, &As[cur ^ 1][off[p]]);
        gl_lds16(gB[p] + kt, &Bs[cur ^ 1][off[p]]);
      }
    }
    const unsigned short* Ac = As[cur];
    const unsigned short* Bc = Bs[cur];
#pragma unroll
    for (int kc = 0; kc < 2; ++kc) {
      bf16x8 af[2], bfr[2];
#pragma unroll
      for (int i = 0; i < 2; ++i)
        af[i] = *(const bf16x8*)&Ac[(wy * 32 + i * 16 + l15) * 64 + ((kc * 4 + quad) ^ xr) * 8];
#pragma unroll
      for (int j = 0; j < 2; ++j)
        bfr[j] = *(const bf16x8*)&Bc[(wx * 32 + j * 16 + l15) * 64 + ((kc * 4 + quad) ^ xr) * 8];
#pragma unroll
      for (int i = 0; i < 2; ++i)
#pragma unroll
        for (int j = 0; j < 2; ++j)
          acc[i][j] = __builtin_amdgcn_mfma_f32_16x16x32_bf16(af[i], bfr[j], acc[i][j], 0, 0, 0);
    }
  }

#pragma unroll
  for (int i = 0; i < 2; ++i) {
    const int row = m0 + wy * 32 + i * 16 + quad * 4;
#pragma unroll
    for (int j = 0; j < 2; ++j) {
      const int col = n0 + wx * 32 + j * 16 + l15;
      const float bv = bias[col];
#pragma unroll
      for (int r = 0; r < 4; ++r)
        Cf[(size_t)(row + r) * N + col] = acc[i][j][r] + bv;
    }
  }
}

// ---------------- flash attention v14: v13 + split P per subtile -----------
// Block = 2 waves x 32 q = 64 q; grid (bh 32, qt 32) = 1024 blocks. DMA dbuf
// XOR-swizzled K/V staging, S^T=KQ^T, O^T=V^T P^T, no-max softmax, l via
// ones-A MFMA, LPT qt=31-y, XCD=bh%8. R18: each q-subtile gets its own
// 16x72 P buffer and the tail is reordered exp0,Pw0,exp1,Pw1,Pr0,PV0,
// Pr1,PV1 — removes the same-address WAR that serialized Pw(tq1) behind
// Pr(tq0). LDS 41.2KB -> 3 blocks/CU (occupancy proven non-binding R16/R17).
__global__ __launch_bounds__(128, 2) void attn_fwd(const unsigned short* __restrict__ qkv,
                                                   const unsigned short* __restrict__ vt,
                                                   unsigned short* __restrict__ o) {
  __shared__ unsigned short Ks[2][64 * 64];
  __shared__ unsigned short Vs[2][64 * 64];
  __shared__ unsigned short pbuf[2][2][16 * 72];  // [wave][subtile][16x72]
  const int tid  = threadIdx.x;
  const int lane = tid & 63;
  const int w    = tid >> 6;          // 2 waves
  const int l15  = lane & 15, quad = lane >> 4;
  const int xr   = l15 & 7;
  const int bh = blockIdx.x, b = bh >> 4, h = bh & 15;
  const int qt = 31 - (int)blockIdx.y;  // LPT order (64-q tiles)
  const int q0 = qt * 64;
  const int qa = q0 + w * 32;
  const int qb = qa + 16;
  const int T = qt + 1;

  // DMA staging: 512 chunks per 64x64 tile / 128 threads = 4/thread/array.
  const unsigned short* gKd[4];
  const unsigned short* gVd[4];
  int doff[4];
#pragma unroll
  for (int p = 0; p < 4; ++p) {
    const int c = tid + p * 128;
    const int r = c >> 3;
    const int sc = ((c & 7) ^ (r & 7)) * 8;
    gKd[p] = qkv + (size_t)(b * 2048 + r) * 3072 + 1024 + h * 64 + sc;
    gVd[p] = vt + (size_t)(bh * 64 + r) * 2048 + sc;
    doff[p] = c * 8;
  }

  const unsigned short* qra = qkv + (size_t)(b * 2048 + qa + l15) * 3072 + h * 64;
  const unsigned short* qrb = qkv + (size_t)(b * 2048 + qb + l15) * 3072 + h * 64;
  const bf16x8 bq[2][2] = {
    { *(const bf16x8*)(qra + quad * 8), *(const bf16x8*)(qra + 32 + quad * 8) },
    { *(const bf16x8*)(qrb + quad * 8), *(const bf16x8*)(qrb + 32 + quad * 8) } };

  bf16x8 vones;
#pragma unroll
  for (int k = 0; k < 8; ++k) vones[k] = (short)0x3F80;  // bf16 1.0

  f32x4 acc[2][4];   // [q-subtile][d-tile] — O^T C-layout: col=q(l15), row=d
#pragma unroll
  for (int i = 0; i < 2; ++i)
#pragma unroll
    for (int j = 0; j < 4; ++j) acc[i][j] = (f32x4){0.f, 0.f, 0.f, 0.f};
  f32x4 accL[2] = {(f32x4){0.f, 0.f, 0.f, 0.f}, (f32x4){0.f, 0.f, 0.f, 0.f}};

  unsigned short* P0 = pbuf[w][0];
  unsigned short* P1 = pbuf[w][1];

  // prologue: DMA tile 0 -> buf 0
#pragma unroll
  for (int p = 0; p < 4; ++p) {
    gl_lds16(gKd[p], &Ks[0][doff[p]]);
    gl_lds16(gVd[p], &Vs[0][doff[p]]);
  }

  for (int t = 0; t < T; ++t) {
    __syncthreads();  // drains DMA for buf(t&1); other buf's reads done
    const int cur = t & 1;
    if (t + 1 < T) {
      const size_t ko = (size_t)(t + 1) * 64 * 3072;
      const int vo = (t + 1) * 64;
#pragma unroll
      for (int p = 0; p < 4; ++p) {
        gl_lds16(gKd[p] + ko, &Ks[cur ^ 1][doff[p]]);
        gl_lds16(gVd[p] + vo, &Vs[cur ^ 1][doff[p]]);
      }
    }
    const unsigned short* Kc = Ks[cur];
    const unsigned short* Vc = Vs[cur];
    const int kv0 = t * 64;

    // ---- S^T[kv][q] = K Q^T for both q-subtiles (K frags swizzled) ----
    f32x4 st[2][4];
#pragma unroll
    for (int n = 0; n < 4; ++n) {
      const int row = n * 16 + l15;
      const bf16x8 kA0 = *(const bf16x8*)&Kc[row * 64 + ((quad) ^ xr) * 8];
      const bf16x8 kA1 = *(const bf16x8*)&Kc[row * 64 + ((4 + quad) ^ xr) * 8];
      f32x4 z0 = (f32x4){0.f, 0.f, 0.f, 0.f};
      z0 = __builtin_amdgcn_mfma_f32_16x16x32_bf16(kA0, bq[0][0], z0, 0, 0, 0);
      z0 = __builtin_amdgcn_mfma_f32_16x16x32_bf16(kA1, bq[0][1], z0, 0, 0, 0);
      st[0][n] = z0;
      f32x4 z1 = (f32x4){0.f, 0.f, 0.f, 0.f};
      z1 = __builtin_amdgcn_mfma_f32_16x16x32_bf16(kA0, bq[1][0], z1, 0, 0, 0);
      z1 = __builtin_amdgcn_mfma_f32_16x16x32_bf16(kA1, bq[1][1], z1, 0, 0, 0);
      st[1][n] = z1;
    }
    // ---- V^T A-frags (swizzled LDS reads, shared by both subtiles) ----
    bf16x8 av[4][2];
#pragma unroll
    for (int j = 0; j < 4; ++j) {
      const int row = j * 16 + l15;
      av[j][0] = *(const bf16x8*)&Vc[row * 64 + ((quad) ^ xr) * 8];
      av[j][1] = *(const bf16x8*)&Vc[row * 64 + ((4 + quad) ^ xr) * 8];
    }
    // ---- mask/exp + P writes for BOTH subtiles (separate buffers) ----
#pragma unroll
    for (int tq = 0; tq < 2; ++tq) {
      unsigned short* P = tq ? P1 : P0;
      const int qbase = tq ? qb : qa;
      if (kv0 + 63 > qbase) {
        const int qrow = qbase + l15;
#pragma unroll
        for (int n = 0; n < 4; ++n)
#pragma unroll
          for (int r = 0; r < 4; ++r)
            if (kv0 + n * 16 + quad * 4 + r > qrow) st[tq][n][r] = -1e30f;
      }
#pragma unroll
      for (int n = 0; n < 4; ++n) {
#pragma unroll
        for (int r = 0; r < 4; ++r) st[tq][n][r] = __expf(st[tq][n][r]);
        u16x4 pw;
        pw[0] = f2b_trunc(st[tq][n][0]); pw[1] = f2b_trunc(st[tq][n][1]);
        pw[2] = f2b_trunc(st[tq][n][2]); pw[3] = f2b_trunc(st[tq][n][3]);
        *(u16x4*)&P[l15 * 72 + n * 16 + quad * 4] = pw;
      }
    }
    // ---- PV for both subtiles (reads pipeline behind the writes) ----
#pragma unroll
    for (int tq = 0; tq < 2; ++tq) {
      const unsigned short* P = tq ? P1 : P0;
      const bf16x8 bp0 = *(const bf16x8*)&P[l15 * 72 + quad * 8];
      const bf16x8 bp1 = *(const bf16x8*)&P[l15 * 72 + 32 + quad * 8];
      accL[tq] = __builtin_amdgcn_mfma_f32_16x16x32_bf16(vones, bp0, accL[tq], 0, 0, 0);
      accL[tq] = __builtin_amdgcn_mfma_f32_16x16x32_bf16(vones, bp1, accL[tq], 0, 0, 0);
#pragma unroll
      for (int j = 0; j < 4; ++j) {
        acc[tq][j] = __builtin_amdgcn_mfma_f32_16x16x32_bf16(av[j][0], bp0, acc[tq][j], 0, 0, 0);
        acc[tq][j] = __builtin_amdgcn_mfma_f32_16x16x32_bf16(av[j][1], bp1, acc[tq][j], 0, 0, 0);
      }
    }
  }
  // ---- epilogue: lane holds q=l15, d=j*16+quad*4+r -> packed u16x4 ----
#pragma unroll
  for (int tq = 0; tq < 2; ++tq) {
    const int qrow = (tq ? qb : qa) + l15;
    const float inv = 1.0f / accL[tq][0];  // all rows of accL equal l[q]
    unsigned short* orow = o + (size_t)(b * 2048 + qrow) * 1024 + h * 64;
#pragma unroll
    for (int j = 0; j < 4; ++j) {
      u16x4 ov;
      ov[0] = f2b(acc[tq][j][0] * inv); ov[1] = f2b(acc[tq][j][1] * inv);
      ov[2] = f2b(acc[tq][j][2] * inv); ov[3] = f2b(acc[tq][j][3] * inv);
      *(u16x4*)(orow + j * 16 + quad * 4) = ov;
    }
  }
}

// ---------------------------------------------------------------------------
extern "C" void kernel_launch(void* const* d_in, const int* in_sizes, int n_in,
                              void* d_out, int out_size, void* d_ws, size_t ws_size,
                              hipStream_t stream) {
  const float* x       = (const float*)d_in[0];
  // d_in[1] = mask: causal tril by construction; implemented analytically.
  const float* w_qkv_w = (const float*)d_in[2];
  const float* w_qkv_b = (const float*)d_in[3];
  const float* w_o_w   = (const float*)d_in[4];
  const float* w_o_b   = (const float*)d_in[5];
  float* out = (float*)d_out;

  unsigned short* ws    = (unsigned short*)d_ws;
  unsigned short* xb    = ws;                                  // 4096*1024
  unsigned short* wqb   = xb   + (size_t)4096 * 1024;          // 3072*1024
  unsigned short* wob   = wqb  + (size_t)3072 * 1024;          // 1024*1024
  unsigned short* qkvb  = wob  + (size_t)1024 * 1024;          // 4096*3072
  unsigned short* vtb   = qkvb + (size_t)4096 * 3072;          // 2048*2048
  unsigned short* attnb = vtb  + (size_t)2048 * 2048;          // 4096*1024

  cvt_all<<<8192, 256, 0, stream>>>(x, w_qkv_w, w_o_w, xb, wqb, wob);
  gemm_bt<<<dim3(24, 32), 256, 0, stream>>>(xb, wqb, w_qkv_b, qkvb, vtb, 4096, 3072, 1024, 1024);
  attn_fwd<<<dim3(32, 32), 128, 0, stream>>>(qkvb, vtb, attnb);
  gemm_bt64<<<dim3(16, 64), 256, 0, stream>>>(attnb, wob, w_o_b, out, 4096, 1024, 1024);
}